// Round 3
// baseline (393.621 us; speedup 1.0000x reference)
//
#include <hip/hip_runtime.h>
#include <hip/hip_bf16.h>
#include <cmath>

// GATv2 encoder, 3 layers, d=64, f32.
// Pipeline per call:
//   1. bucketed dst-CSR build: 64-dst buckets, XCD-subslotted partition
//      (kills the 55MB random-write amplification), per-bucket LDS hist+scan.
//   2. per layer: transform (xl=h@Wl+bl, xr=h@Wr+br), then one-wave-per-node
//      chain-free chunked softmax edge aggregation fused with bias+ReLU+residual.

#define D 64
#define NSUB 8   // sub-slots per bucket, indexed by blockIdx&7 (~XCD id)

// ---------------- CSR build ----------------

// P1: histogram into (bucket, sub) bins
__global__ __launch_bounds__(256) void hist2_kernel(
    const int* __restrict__ ei, int* __restrict__ h2, int E, int N) {
  int eid = blockIdx.x * 256 + threadIdx.x;
  if (eid >= E + N) return;
  int d = (eid < E) ? ei[E + eid] : (eid - E);
  atomicAdd(&h2[(d >> 6) * NSUB + (blockIdx.x & 7)], 1);
}

// P2: exclusive scan of the M = NB*NSUB bin counts -> sub_base, cursor2
__global__ __launch_bounds__(1024) void scanbins_kernel(
    const int* __restrict__ h2, int* __restrict__ sub_base,
    int* __restrict__ cursor2, int M) {
  int tid = threadIdx.x;
  int chunk = (M + 1023) / 1024;
  int beg = tid * chunk;
  int end = min(M, beg + chunk);
  int sum = 0;
  for (int i = beg; i < end; ++i) sum += h2[i];
  int lane = tid & 63, w = tid >> 6;
  int v = sum;
#pragma unroll
  for (int o = 1; o < 64; o <<= 1) {
    int t = __shfl_up(v, o, 64);
    if (lane >= o) v += t;
  }
  __shared__ int wsum[16], woff[16];
  if (lane == 63) wsum[w] = v;
  __syncthreads();
  if (tid == 0) { int r = 0; for (int i = 0; i < 16; ++i) { woff[i] = r; r += wsum[i]; } }
  __syncthreads();
  int run = woff[w] + (v - sum);
  for (int i = beg; i < end; ++i) {
    sub_base[i] = run;
    cursor2[i] = run;
    run += h2[i];
  }
}

// P3: partition edge records into bucket/sub regions.
// record = (dst&63)<<26 | src   (src < 2^26)
__global__ __launch_bounds__(256) void partition_kernel(
    const int* __restrict__ ei, int* __restrict__ cursor2,
    unsigned* __restrict__ rec, int E, int N) {
  int eid = blockIdx.x * 256 + threadIdx.x;
  if (eid >= E + N) return;
  int s, d;
  if (eid < E) { s = ei[eid]; d = ei[E + eid]; }
  else         { s = d = eid - E; }
  int pos = atomicAdd(&cursor2[(d >> 6) * NSUB + (blockIdx.x & 7)], 1);
  rec[pos] = ((unsigned)(d & 63) << 26) | (unsigned)s;
}

// P4: one block per bucket: LDS hist of 64 dsts -> scan -> rowptr + scatter
// within the bucket's contiguous csr region (single-block writes: L2-coalesced).
__global__ __launch_bounds__(256) void buildcsr_kernel(
    const unsigned* __restrict__ rec, const int* __restrict__ sub_base,
    int* __restrict__ rowptr, int* __restrict__ csr_src,
    int N, int EP, int NB) {
  int b = blockIdx.x;
  int tid = threadIdx.x;
  int bb = sub_base[b * NSUB];
  int be = (b == NB - 1) ? EP : sub_base[(b + 1) * NSUB];
  __shared__ int ldeg[64], lcur[64];
  if (tid < 64) ldeg[tid] = 0;
  __syncthreads();
  for (int p = bb + tid; p < be; p += 256)
    atomicAdd(&ldeg[rec[p] >> 26], 1);
  __syncthreads();
  if (tid < 64) {   // wave 0 exactly: full-wave shuffle scan
    int dv = ldeg[tid];
    int inc = dv;
#pragma unroll
    for (int o = 1; o < 64; o <<= 1) {
      int t = __shfl_up(inc, o, 64);
      if (tid >= o) inc += t;
    }
    int excl = inc - dv;
    lcur[tid] = excl;
    int idx = b * 64 + tid;
    if (idx < N) rowptr[idx] = bb + excl;
  }
  if (b == 0 && tid == 0) rowptr[N] = EP;
  __syncthreads();
  for (int p = bb + tid; p < be; p += 256) {
    unsigned r = rec[p];
    int pos = bb + atomicAdd(&lcur[r >> 26], 1);
    csr_src[pos] = (int)(r & 0x3FFFFFFu);
  }
}

// ---------------- per-layer transform: xl = h@Wl+bl, xr = h@Wr+br ----------------

__global__ __launch_bounds__(256) void transform_kernel(
    const float* __restrict__ h,
    const float* __restrict__ Wl, const float* __restrict__ bl,
    const float* __restrict__ Wr, const float* __restrict__ br,
    float* __restrict__ xl, float* __restrict__ xr, int N) {
  __shared__ float hs[16][D];
  int tid = threadIdx.x;
  int j = tid & 63;
  float wl[D], wr[D];
#pragma unroll
  for (int k = 0; k < D; ++k) {
    wl[k] = Wl[k * D + j];
    wr[k] = Wr[k * D + j];
  }
  int node0 = blockIdx.x * 16;
  for (int i = tid; i < 16 * D; i += 256) {
    int n = node0 + (i >> 6);
    hs[i >> 6][i & 63] = (n < N) ? h[(size_t)n * D + (i & 63)] : 0.f;
  }
  __syncthreads();
  float blj = bl[j], brj = br[j];
  int nl = tid >> 6;
  for (int g = 0; g < 4; ++g) {
    int local = nl * 4 + g;
    int n = node0 + local;
    float al = blj, ar = brj;
#pragma unroll
    for (int k4 = 0; k4 < D / 4; ++k4) {
      float4 hv = *reinterpret_cast<const float4*>(&hs[local][k4 * 4]);
      al = fmaf(hv.x, wl[k4 * 4 + 0], al);
      ar = fmaf(hv.x, wr[k4 * 4 + 0], ar);
      al = fmaf(hv.y, wl[k4 * 4 + 1], al);
      ar = fmaf(hv.y, wr[k4 * 4 + 1], ar);
      al = fmaf(hv.z, wl[k4 * 4 + 2], al);
      ar = fmaf(hv.z, wr[k4 * 4 + 2], ar);
      al = fmaf(hv.w, wl[k4 * 4 + 3], al);
      ar = fmaf(hv.w, wr[k4 * 4 + 3], ar);
    }
    if (n < N) {
      xl[(size_t)n * D + j] = al;
      xr[(size_t)n * D + j] = ar;
    }
  }
}

// ---------------- edge aggregation ----------------
// One wave per dst node; 16 lanes per edge (float4 features/lane).
// Chunked chain-free softmax: per <=32-edge chunk, gather all xu into regs,
// stash score of edge e in lane e, ONE exp for the chunk, then weighted
// accumulation. Online merge only across chunks (deg>32, rare).

__global__ __launch_bounds__(256) void edge_kernel(
    const float* __restrict__ xl, const float* __restrict__ xr,
    const float* __restrict__ h_in, const int* __restrict__ rowptr,
    const int* __restrict__ csr_src, const float* __restrict__ att,
    const float* __restrict__ bias, float* __restrict__ h_out, int N) {
  int wid = (blockIdx.x * blockDim.x + threadIdx.x) >> 6;
  if (wid >= N) return;
  int lane = threadIdx.x & 63;
  int g = lane >> 4;          // edge group within a 4-edge batch
  int l16 = lane & 15;        // feature-quad index
  int v = wid;
  float4 xr4 = *reinterpret_cast<const float4*>(&xr[(size_t)v * D + l16 * 4]);
  float4 at4 = *reinterpret_cast<const float4*>(&att[l16 * 4]);
  int beg = rowptr[v], end = rowptr[v + 1];
  float m = -INFINITY, s = 0.f;
  float ax = 0.f, ay = 0.f, az = 0.f, aw = 0.f;
  for (int tb = beg; tb < end; tb += 64) {
    int nt64 = min(64, end - tb);
    int us = (tb + lane < end) ? csr_src[tb + lane] : 0;  // coalesced src batch
    for (int half = 0; half < 2 && half * 32 < nt64; ++half) {
      int base = half * 32;
      int nt = min(32, nt64 - base);          // edges in this chunk
      int nb4 = (nt + 3) >> 2;                // 4-edge batches
      float4 xu[8];
      float psel = -INFINITY;                 // lane e holds score of edge e
#pragma unroll
      for (int i = 0; i < 8; ++i) {
        xu[i] = make_float4(0.f, 0.f, 0.f, 0.f);
        if (i < nb4) {
          int u = __shfl(us, base + 4 * i + g, 64);
          if (4 * i + g < nt)
            xu[i] = *reinterpret_cast<const float4*>(&xl[(size_t)u * D + l16 * 4]);
          float tx = xu[i].x + xr4.x, ty = xu[i].y + xr4.y;
          float tz = xu[i].z + xr4.z, tw = xu[i].w + xr4.w;
          tx = (tx > 0.f) ? tx : 0.2f * tx;   // leaky_relu, slope 0.2
          ty = (ty > 0.f) ? ty : 0.2f * ty;
          tz = (tz > 0.f) ? tz : 0.2f * tz;
          tw = (tw > 0.f) ? tw : 0.2f * tw;
          float p = tx * at4.x + ty * at4.y + tz * at4.z + tw * at4.w;
          p += __shfl_xor(p, 1, 64);          // reduce over 16-lane group
          p += __shfl_xor(p, 2, 64);
          p += __shfl_xor(p, 4, 64);
          p += __shfl_xor(p, 8, 64);
          float pg = __shfl(p, (lane & 3) << 4, 64);  // group (lane&3)'s score
          if ((lane >> 2) == i && lane < nt) psel = pg;
        }
      }
      // chunk max, one exp, chunk sum, merge with running state
      float cm = psel;
#pragma unroll
      for (int o = 32; o > 0; o >>= 1) cm = fmaxf(cm, __shfl_xor(cm, o, 64));
      float mn = fmaxf(m, cm);
      float a = __expf(m - mn);               // first chunk: exp(-inf)=0
      float bsc = __expf(cm - mn);
      float w = __expf(psel - cm) * bsc;      // lane e: weight of edge e (0 if invalid)
      float cs = w;
#pragma unroll
      for (int o = 32; o > 0; o >>= 1) cs += __shfl_xor(cs, o, 64);
      s = s * a + cs;
      ax *= a; ay *= a; az *= a; aw *= a;
#pragma unroll
      for (int i = 0; i < 8; ++i) {
        if (i < nb4) {
          float wi = __shfl(w, 4 * i + g, 64);   // this group's edge weight
          ax = fmaf(wi, xu[i].x, ax);
          ay = fmaf(wi, xu[i].y, ay);
          az = fmaf(wi, xu[i].z, az);
          aw = fmaf(wi, xu[i].w, aw);
        }
      }
      m = mn;
    }
  }
  // combine per-group partials (same feature slots, different edges)
  ax += __shfl_xor(ax, 16, 64); ax += __shfl_xor(ax, 32, 64);
  ay += __shfl_xor(ay, 16, 64); ay += __shfl_xor(ay, 32, 64);
  az += __shfl_xor(az, 16, 64); az += __shfl_xor(az, 32, 64);
  aw += __shfl_xor(aw, 16, 64); aw += __shfl_xor(aw, 32, 64);
  if (g == 0) {
    float4 b4v = *reinterpret_cast<const float4*>(&bias[l16 * 4]);
    float4 hv  = *reinterpret_cast<const float4*>(&h_in[(size_t)v * D + l16 * 4]);
    float inv = 1.f / s;
    float4 o;
    o.x = fmaxf(ax * inv + b4v.x, 0.f) + hv.x;
    o.y = fmaxf(ay * inv + b4v.y, 0.f) + hv.y;
    o.z = fmaxf(az * inv + b4v.z, 0.f) + hv.z;
    o.w = fmaxf(aw * inv + b4v.w, 0.f) + hv.w;
    *reinterpret_cast<float4*>(&h_out[(size_t)v * D + l16 * 4]) = o;
  }
}

// ---------------- launch ----------------

extern "C" void kernel_launch(void* const* d_in, const int* in_sizes, int n_in,
                              void* d_out, int out_size, void* d_ws, size_t ws_size,
                              hipStream_t stream) {
  const float* x    = (const float*)d_in[0];
  const int*   ei   = (const int*)d_in[1];
  const float* Wl   = (const float*)d_in[2];
  const float* bl   = (const float*)d_in[3];
  const float* Wr   = (const float*)d_in[4];
  const float* br   = (const float*)d_in[5];
  const float* att  = (const float*)d_in[6];
  const float* bias = (const float*)d_in[7];

  int N = in_sizes[0] / D;
  int E = in_sizes[1] / 2;
  int L = in_sizes[2] / (D * D);
  int EP = E + N;
  int NB = (N + 63) >> 6;          // 64-dst buckets
  int M = NB * NSUB;
  int nbE = (EP + 255) / 256;

  float* xl = (float*)d_ws;
  float* xr = xl + (size_t)N * D;
  float* hA = xr + (size_t)N * D;
  float* hB = hA + (size_t)N * D;
  unsigned* rec = (unsigned*)(hB + (size_t)N * D);
  int* csr_src  = (int*)(rec + EP);
  int* rowptr   = csr_src + EP;
  int* h2       = rowptr + (N + 1);
  int* sub_base = h2 + M;
  int* cursor2  = sub_base + M;

  // CSR build (graph is layer-invariant: build once per call)
  hipMemsetAsync(h2, 0, (size_t)M * sizeof(int), stream);
  hist2_kernel<<<nbE, 256, 0, stream>>>(ei, h2, E, N);
  scanbins_kernel<<<1, 1024, 0, stream>>>(h2, sub_base, cursor2, M);
  partition_kernel<<<nbE, 256, 0, stream>>>(ei, cursor2, rec, E, N);
  buildcsr_kernel<<<NB, 256, 0, stream>>>(rec, sub_base, rowptr, csr_src, N, EP, NB);

  const float* h_in = x;
  for (int l = 0; l < L; ++l) {
    float* h_out = (l == L - 1) ? (float*)d_out : ((l % 2 == 0) ? hA : hB);
    transform_kernel<<<(N + 15) / 16, 256, 0, stream>>>(
        h_in, Wl + (size_t)l * D * D, bl + (size_t)l * D,
        Wr + (size_t)l * D * D, br + (size_t)l * D, xl, xr, N);
    edge_kernel<<<((N + 3) / 4), 256, 0, stream>>>(
        xl, xr, h_in, rowptr, csr_src, att + (size_t)l * D,
        bias + (size_t)l * D, h_out, N);
    h_in = h_out;
  }
}

// Round 4
// 283.985 us; speedup vs baseline: 1.3861x; 1.3861x over previous
//
#include <hip/hip_runtime.h>
#include <hip/hip_bf16.h>
#include <cmath>

// GATv2 encoder, 3 layers, d=64, f32 in/out.
//   1. bucketed dst-CSR build (64-dst buckets, XCD-subslotted partition).
//   2. per layer: transform (xlh = bf16(h@Wl+bl) gather table, xr = h@Wr+br),
//      then edge aggregation: 4 nodes per wave (16-lane groups), group-local
//      online softmax over 4-edge chunks, bf16 gathers, fused bias+ReLU+residual.

#define D 64
#define NSUB 8   // sub-slots per bucket, indexed by blockIdx&7 (~XCD id)

// ---------------- CSR build ----------------

__global__ __launch_bounds__(256) void hist2_kernel(
    const int* __restrict__ ei, int* __restrict__ h2, int E, int N) {
  int eid = blockIdx.x * 256 + threadIdx.x;
  if (eid >= E + N) return;
  int d = (eid < E) ? ei[E + eid] : (eid - E);
  atomicAdd(&h2[(d >> 6) * NSUB + (blockIdx.x & 7)], 1);
}

__global__ __launch_bounds__(1024) void scanbins_kernel(
    const int* __restrict__ h2, int* __restrict__ sub_base,
    int* __restrict__ cursor2, int M) {
  int tid = threadIdx.x;
  int chunk = (M + 1023) / 1024;
  int beg = tid * chunk;
  int end = min(M, beg + chunk);
  int sum = 0;
  for (int i = beg; i < end; ++i) sum += h2[i];
  int lane = tid & 63, w = tid >> 6;
  int v = sum;
#pragma unroll
  for (int o = 1; o < 64; o <<= 1) {
    int t = __shfl_up(v, o, 64);
    if (lane >= o) v += t;
  }
  __shared__ int wsum[16], woff[16];
  if (lane == 63) wsum[w] = v;
  __syncthreads();
  if (tid == 0) { int r = 0; for (int i = 0; i < 16; ++i) { woff[i] = r; r += wsum[i]; } }
  __syncthreads();
  int run = woff[w] + (v - sum);
  for (int i = beg; i < end; ++i) {
    sub_base[i] = run;
    cursor2[i] = run;
    run += h2[i];
  }
}

// record = (dst&63)<<26 | src   (src < 2^26)
__global__ __launch_bounds__(256) void partition_kernel(
    const int* __restrict__ ei, int* __restrict__ cursor2,
    unsigned* __restrict__ rec, int E, int N) {
  int eid = blockIdx.x * 256 + threadIdx.x;
  if (eid >= E + N) return;
  int s, d;
  if (eid < E) { s = ei[eid]; d = ei[E + eid]; }
  else         { s = d = eid - E; }
  int pos = atomicAdd(&cursor2[(d >> 6) * NSUB + (blockIdx.x & 7)], 1);
  rec[pos] = ((unsigned)(d & 63) << 26) | (unsigned)s;
}

__global__ __launch_bounds__(256) void buildcsr_kernel(
    const unsigned* __restrict__ rec, const int* __restrict__ sub_base,
    int* __restrict__ rowptr, int* __restrict__ csr_src,
    int N, int EP, int NB) {
  int b = blockIdx.x;
  int tid = threadIdx.x;
  int bb = sub_base[b * NSUB];
  int be = (b == NB - 1) ? EP : sub_base[(b + 1) * NSUB];
  __shared__ int ldeg[64], lcur[64];
  if (tid < 64) ldeg[tid] = 0;
  __syncthreads();
  for (int p = bb + tid; p < be; p += 256)
    atomicAdd(&ldeg[rec[p] >> 26], 1);
  __syncthreads();
  if (tid < 64) {   // wave 0 exactly: full-wave shuffle scan
    int dv = ldeg[tid];
    int inc = dv;
#pragma unroll
    for (int o = 1; o < 64; o <<= 1) {
      int t = __shfl_up(inc, o, 64);
      if (tid >= o) inc += t;
    }
    int excl = inc - dv;
    lcur[tid] = excl;
    int idx = b * 64 + tid;
    if (idx < N) rowptr[idx] = bb + excl;
  }
  if (b == 0 && tid == 0) rowptr[N] = EP;
  __syncthreads();
  for (int p = bb + tid; p < be; p += 256) {
    unsigned r = rec[p];
    int pos = bb + atomicAdd(&lcur[r >> 26], 1);
    csr_src[pos] = (int)(r & 0x3FFFFFFu);
  }
}

// ---------------- transform: xlh = bf16(h@Wl+bl), xr = h@Wr+br ----------------

__device__ __forceinline__ unsigned short f2bf(float f) {
  unsigned u = __float_as_uint(f);
  return (unsigned short)((u + 0x7FFFu + ((u >> 16) & 1u)) >> 16);  // RNE
}

__global__ __launch_bounds__(256) void transform_kernel(
    const float* __restrict__ h,
    const float* __restrict__ Wl, const float* __restrict__ bl,
    const float* __restrict__ Wr, const float* __restrict__ br,
    unsigned short* __restrict__ xlh, float* __restrict__ xr, int N) {
  __shared__ float hs[16][D];
  int tid = threadIdx.x;
  int j = tid & 63;
  float wl[D], wr[D];
#pragma unroll
  for (int k = 0; k < D; ++k) {
    wl[k] = Wl[k * D + j];
    wr[k] = Wr[k * D + j];
  }
  int node0 = blockIdx.x * 16;
  for (int i = tid; i < 16 * D; i += 256) {
    int n = node0 + (i >> 6);
    hs[i >> 6][i & 63] = (n < N) ? h[(size_t)n * D + (i & 63)] : 0.f;
  }
  __syncthreads();
  float blj = bl[j], brj = br[j];
  int nl = tid >> 6;
  for (int g = 0; g < 4; ++g) {
    int local = nl * 4 + g;
    int n = node0 + local;
    float al = blj, ar = brj;
#pragma unroll
    for (int k4 = 0; k4 < D / 4; ++k4) {
      float4 hv = *reinterpret_cast<const float4*>(&hs[local][k4 * 4]);
      al = fmaf(hv.x, wl[k4 * 4 + 0], al);
      ar = fmaf(hv.x, wr[k4 * 4 + 0], ar);
      al = fmaf(hv.y, wl[k4 * 4 + 1], al);
      ar = fmaf(hv.y, wr[k4 * 4 + 1], ar);
      al = fmaf(hv.z, wl[k4 * 4 + 2], al);
      ar = fmaf(hv.z, wr[k4 * 4 + 2], ar);
      al = fmaf(hv.w, wl[k4 * 4 + 3], al);
      ar = fmaf(hv.w, wr[k4 * 4 + 3], ar);
    }
    if (n < N) {
      xlh[(size_t)n * D + j] = f2bf(al);
      xr[(size_t)n * D + j] = ar;
    }
  }
}

// ---------------- edge aggregation ----------------
// Wave = 4 nodes; 16-lane group per node (float4 features/lane, bf16 gathers).
// Per group: online softmax over 4-edge chunks (4 gathers in flight),
// csr_src read 16-ahead. Fused bias+ReLU+residual epilogue.

__global__ __launch_bounds__(256) void edge_kernel(
    const unsigned short* __restrict__ xlh, const float* __restrict__ xr,
    const float* __restrict__ h_in, const int* __restrict__ rowptr,
    const int* __restrict__ csr_src, const float* __restrict__ att,
    const float* __restrict__ bias, float* __restrict__ h_out, int N) {
  int wv = (blockIdx.x * blockDim.x + threadIdx.x) >> 6;
  int lane = threadIdx.x & 63;
  int g = lane >> 4, l16 = lane & 15;
  int v = wv * 4 + g;
  if (v >= N) return;
  float4 xr4 = *reinterpret_cast<const float4*>(&xr[(size_t)v * D + l16 * 4]);
  float4 at4 = *reinterpret_cast<const float4*>(&att[l16 * 4]);
  int beg = rowptr[v], end = rowptr[v + 1];
  int deg = end - beg;                       // >= 1 (self-loop)
  int glane0 = g << 4;
  float m = -INFINITY, s = 0.f;
  float ax = 0.f, ay = 0.f, az = 0.f, aw = 0.f;
  for (int sc = 0; sc < deg; sc += 16) {
    int us = csr_src[min(beg + sc + l16, end - 1)];   // 16 srcs ahead (clamped)
    int nt = min(16, deg - sc);
    for (int cc = 0; cc < nt; cc += 4) {
      float4 xu[4];
      float p[4];
#pragma unroll
      for (int k = 0; k < 4; ++k) {
        int u = __shfl(us, glane0 + cc + k, 64);      // group-local broadcast
        uint2 q = *reinterpret_cast<const uint2*>(&xlh[(size_t)u * D + l16 * 4]);
        xu[k].x = __uint_as_float(q.x << 16);
        xu[k].y = __uint_as_float(q.x & 0xFFFF0000u);
        xu[k].z = __uint_as_float(q.y << 16);
        xu[k].w = __uint_as_float(q.y & 0xFFFF0000u);
        float tx = xu[k].x + xr4.x, ty = xu[k].y + xr4.y;
        float tz = xu[k].z + xr4.z, tw = xu[k].w + xr4.w;
        tx = fmaxf(tx, 0.2f * tx);                    // leaky_relu slope 0.2
        ty = fmaxf(ty, 0.2f * ty);
        tz = fmaxf(tz, 0.2f * tz);
        tw = fmaxf(tw, 0.2f * tw);
        float pp = tx * at4.x + ty * at4.y + tz * at4.z + tw * at4.w;
        pp += __shfl_xor(pp, 1, 64);                  // 16-lane group reduce
        pp += __shfl_xor(pp, 2, 64);
        pp += __shfl_xor(pp, 4, 64);
        pp += __shfl_xor(pp, 8, 64);
        p[k] = (cc + k < nt) ? pp : -INFINITY;
      }
      float pm = fmaxf(fmaxf(p[0], p[1]), fmaxf(p[2], p[3]));
      float mn = fmaxf(m, pm);
      float a  = __expf(m - mn);                      // first chunk: 0
      float w0 = __expf(p[0] - mn);                   // invalid -> 0
      float w1 = __expf(p[1] - mn);
      float w2 = __expf(p[2] - mn);
      float w3 = __expf(p[3] - mn);
      s = s * a + (w0 + w1) + (w2 + w3);
      ax = fmaf(w0, xu[0].x, fmaf(w1, xu[1].x, fmaf(w2, xu[2].x, fmaf(w3, xu[3].x, ax * a))));
      ay = fmaf(w0, xu[0].y, fmaf(w1, xu[1].y, fmaf(w2, xu[2].y, fmaf(w3, xu[3].y, ay * a))));
      az = fmaf(w0, xu[0].z, fmaf(w1, xu[1].z, fmaf(w2, xu[2].z, fmaf(w3, xu[3].z, az * a))));
      aw = fmaf(w0, xu[0].w, fmaf(w1, xu[1].w, fmaf(w2, xu[2].w, fmaf(w3, xu[3].w, aw * a))));
      m = mn;
    }
  }
  float inv = 1.f / s;
  float4 b4v = *reinterpret_cast<const float4*>(&bias[l16 * 4]);
  float4 hv  = *reinterpret_cast<const float4*>(&h_in[(size_t)v * D + l16 * 4]);
  float4 o;
  o.x = fmaxf(ax * inv + b4v.x, 0.f) + hv.x;
  o.y = fmaxf(ay * inv + b4v.y, 0.f) + hv.y;
  o.z = fmaxf(az * inv + b4v.z, 0.f) + hv.z;
  o.w = fmaxf(aw * inv + b4v.w, 0.f) + hv.w;
  *reinterpret_cast<float4*>(&h_out[(size_t)v * D + l16 * 4]) = o;
}

// ---------------- launch ----------------

extern "C" void kernel_launch(void* const* d_in, const int* in_sizes, int n_in,
                              void* d_out, int out_size, void* d_ws, size_t ws_size,
                              hipStream_t stream) {
  const float* x    = (const float*)d_in[0];
  const int*   ei   = (const int*)d_in[1];
  const float* Wl   = (const float*)d_in[2];
  const float* bl   = (const float*)d_in[3];
  const float* Wr   = (const float*)d_in[4];
  const float* br   = (const float*)d_in[5];
  const float* att  = (const float*)d_in[6];
  const float* bias = (const float*)d_in[7];

  int N = in_sizes[0] / D;
  int E = in_sizes[1] / 2;
  int L = in_sizes[2] / (D * D);
  int EP = E + N;
  int NB = (N + 63) >> 6;          // 64-dst buckets
  int M = NB * NSUB;
  int nbE = (EP + 255) / 256;

  float* xr = (float*)d_ws;
  float* hA = xr + (size_t)N * D;
  float* hB = hA + (size_t)N * D;
  unsigned short* xlh = (unsigned short*)(hB + (size_t)N * D);
  unsigned* rec = (unsigned*)(xlh + (size_t)N * D);
  int* csr_src  = (int*)(rec + EP);
  int* rowptr   = csr_src + EP;
  int* h2       = rowptr + (N + 1);
  int* sub_base = h2 + M;
  int* cursor2  = sub_base + M;

  // CSR build (graph is layer-invariant: build once per call)
  hipMemsetAsync(h2, 0, (size_t)M * sizeof(int), stream);
  hist2_kernel<<<nbE, 256, 0, stream>>>(ei, h2, E, N);
  scanbins_kernel<<<1, 1024, 0, stream>>>(h2, sub_base, cursor2, M);
  partition_kernel<<<nbE, 256, 0, stream>>>(ei, cursor2, rec, E, N);
  buildcsr_kernel<<<NB, 256, 0, stream>>>(rec, sub_base, rowptr, csr_src, N, EP, NB);

  int nwaves = (N + 3) / 4;                 // 4 nodes per wave
  int nblocks = (nwaves * 64 + 255) / 256;
  const float* h_in = x;
  for (int l = 0; l < L; ++l) {
    float* h_out = (l == L - 1) ? (float*)d_out : ((l % 2 == 0) ? hA : hB);
    transform_kernel<<<(N + 15) / 16, 256, 0, stream>>>(
        h_in, Wl + (size_t)l * D * D, bl + (size_t)l * D,
        Wr + (size_t)l * D * D, br + (size_t)l * D, xlh, xr, N);
    edge_kernel<<<nblocks, 256, 0, stream>>>(
        xlh, xr, h_in, rowptr, csr_src, att + (size_t)l * D,
        bias + (size_t)l * D, h_out, N);
    h_in = h_out;
  }
}

// Round 5
// 223.410 us; speedup vs baseline: 1.7619x; 1.2711x over previous
//
#include <hip/hip_runtime.h>
#include <hip/hip_bf16.h>
#include <cmath>

// GATv2 encoder, 3 layers, d=64, f32 in/out.
//   1. dst-CSR build via two-level partition:
//      coarse (49 x 1024-dst buckets, per-block LDS hist + contiguous ~136B
//      runs -> no write amplification), then per-coarse-bucket fine CSR
//      (LDS hist[1024] + scan + L2-local scatter).
//   2. per layer: transform (xlh = bf16(h@Wl+bl) gather table, xr = h@Wr+br),
//      then edge aggregation: 4 nodes/wave, 16-lane groups, group-local online
//      softmax over 4-edge chunks, bf16 gathers, fused bias+ReLU+residual.

#define D 64
#define CB 10              // coarse bucket = 1024 dsts (dst >> CB); N <= 65536
#define NBLK 512           // persistent blocks for coarse hist/scatter

// ---------------- CSR build ----------------

// C1: per-block coarse histogram. ghist[c*NBLK + blk] = count.
__global__ __launch_bounds__(256) void hist_coarse_kernel(
    const int* __restrict__ ei, int* __restrict__ ghist, int E, int N, int NC) {
  __shared__ int h[64];
  int tid = threadIdx.x, blk = blockIdx.x;
  if (tid < 64) h[tid] = 0;
  __syncthreads();
  for (int eid = blk * 256 + tid; eid < E + N; eid += NBLK * 256) {
    int d = (eid < E) ? ei[E + eid] : (eid - E);
    atomicAdd(&h[d >> CB], 1);
  }
  __syncthreads();
  if (tid < NC) ghist[tid * NBLK + blk] = h[tid];
}

// C2: exclusive scan of M = NC*NBLK counts in place; emit cbase[c] (+ cbase[NC]).
__global__ __launch_bounds__(1024) void scan_coarse_kernel(
    int* __restrict__ g, int* __restrict__ cbase, int M, int NC, int EP) {
  int tid = threadIdx.x;
  int chunk = (M + 1023) / 1024;
  int beg = tid * chunk;
  int end = min(M, beg + chunk);
  int sum = 0;
  for (int i = beg; i < end; ++i) sum += g[i];
  int lane = tid & 63, w = tid >> 6;
  int v = sum;
#pragma unroll
  for (int o = 1; o < 64; o <<= 1) {
    int t = __shfl_up(v, o, 64);
    if (lane >= o) v += t;
  }
  __shared__ int wsum[16], woff[16];
  if (lane == 63) wsum[w] = v;
  __syncthreads();
  if (tid == 0) { int r = 0; for (int i = 0; i < 16; ++i) { woff[i] = r; r += wsum[i]; } }
  __syncthreads();
  int run = woff[w] + (v - sum);
  for (int i = beg; i < end; ++i) {
    int old = g[i];
    g[i] = run;
    if ((i & (NBLK - 1)) == 0) cbase[i / NBLK] = run;
    run += old;
  }
  if (tid == 0) cbase[NC] = EP;
}

// C3: coarse scatter. Same grid-stride mapping as C1; per-(block,bucket) runs
// are ~34 contiguous records -> full-line writes. rec = (dst&1023)<<16 | src.
__global__ __launch_bounds__(256) void scatter_coarse_kernel(
    const int* __restrict__ ei, const int* __restrict__ g,
    unsigned* __restrict__ rec, int E, int N, int NC) {
  __shared__ int cur[64];
  int tid = threadIdx.x, blk = blockIdx.x;
  if (tid < NC) cur[tid] = g[tid * NBLK + blk];
  __syncthreads();
  for (int eid = blk * 256 + tid; eid < E + N; eid += NBLK * 256) {
    int s, d;
    if (eid < E) { s = ei[eid]; d = ei[E + eid]; }
    else         { s = d = eid - E; }
    int pos = atomicAdd(&cur[d >> CB], 1);
    rec[pos] = ((unsigned)(d & ((1 << CB) - 1)) << 16) | (unsigned)s;
  }
}

// C4: one block per coarse bucket: LDS hist of 1024 dsts -> scan -> rowptr +
// scatter within the bucket's contiguous (L2-local) region.
__global__ __launch_bounds__(1024) void buildcsr2_kernel(
    const unsigned* __restrict__ rec, const int* __restrict__ cbase,
    int* __restrict__ rowptr, int* __restrict__ csr_src, int N, int EP) {
  int c = blockIdx.x, tid = threadIdx.x;
  int bb = cbase[c], be = cbase[c + 1];
  __shared__ int hist[1024], cur[1024];
  hist[tid] = 0;
  __syncthreads();
  for (int p = bb + tid; p < be; p += 1024)
    atomicAdd(&hist[rec[p] >> 16], 1);
  __syncthreads();
  int dv = hist[tid];
  int lane = tid & 63, w = tid >> 6;
  int inc = dv;
#pragma unroll
  for (int o = 1; o < 64; o <<= 1) {
    int t = __shfl_up(inc, o, 64);
    if (lane >= o) inc += t;
  }
  __shared__ int wsum[16], woff[16];
  if (lane == 63) wsum[w] = inc;
  __syncthreads();
  if (tid == 0) { int r = 0; for (int i = 0; i < 16; ++i) { woff[i] = r; r += wsum[i]; } }
  __syncthreads();
  int excl = woff[w] + inc - dv;
  cur[tid] = excl;
  int node = (c << CB) + tid;
  if (node < N) rowptr[node] = bb + excl;
  if (c == 0 && tid == 0) rowptr[N] = EP;
  __syncthreads();
  for (int p = bb + tid; p < be; p += 1024) {
    unsigned r = rec[p];
    int pos = bb + atomicAdd(&cur[r >> 16], 1);
    csr_src[pos] = (int)(r & 0xFFFFu);
  }
}

// ---------------- transform: xlh = bf16(h@Wl+bl), xr = h@Wr+br ----------------

__device__ __forceinline__ unsigned short f2bf(float f) {
  unsigned u = __float_as_uint(f);
  return (unsigned short)((u + 0x7FFFu + ((u >> 16) & 1u)) >> 16);  // RNE
}

__global__ __launch_bounds__(256) void transform_kernel(
    const float* __restrict__ h,
    const float* __restrict__ Wl, const float* __restrict__ bl,
    const float* __restrict__ Wr, const float* __restrict__ br,
    unsigned short* __restrict__ xlh, float* __restrict__ xr, int N) {
  __shared__ float hs[16][D];
  int tid = threadIdx.x;
  int j = tid & 63;
  float wl[D], wr[D];
#pragma unroll
  for (int k = 0; k < D; ++k) {
    wl[k] = Wl[k * D + j];
    wr[k] = Wr[k * D + j];
  }
  int node0 = blockIdx.x * 16;
  for (int i = tid; i < 16 * D; i += 256) {
    int n = node0 + (i >> 6);
    hs[i >> 6][i & 63] = (n < N) ? h[(size_t)n * D + (i & 63)] : 0.f;
  }
  __syncthreads();
  float blj = bl[j], brj = br[j];
  int nl = tid >> 6;
  for (int g = 0; g < 4; ++g) {
    int local = nl * 4 + g;
    int n = node0 + local;
    float al = blj, ar = brj;
#pragma unroll
    for (int k4 = 0; k4 < D / 4; ++k4) {
      float4 hv = *reinterpret_cast<const float4*>(&hs[local][k4 * 4]);
      al = fmaf(hv.x, wl[k4 * 4 + 0], al);
      ar = fmaf(hv.x, wr[k4 * 4 + 0], ar);
      al = fmaf(hv.y, wl[k4 * 4 + 1], al);
      ar = fmaf(hv.y, wr[k4 * 4 + 1], ar);
      al = fmaf(hv.z, wl[k4 * 4 + 2], al);
      ar = fmaf(hv.z, wr[k4 * 4 + 2], ar);
      al = fmaf(hv.w, wl[k4 * 4 + 3], al);
      ar = fmaf(hv.w, wr[k4 * 4 + 3], ar);
    }
    if (n < N) {
      xlh[(size_t)n * D + j] = f2bf(al);
      xr[(size_t)n * D + j] = ar;
    }
  }
}

// ---------------- edge aggregation ----------------
// Wave = 4 nodes; 16-lane group per node (float4 features/lane, bf16 gathers).
// Per group: online softmax over 4-edge chunks (4 gathers in flight),
// csr_src read 16-ahead. Fused bias+ReLU+residual epilogue.

__global__ __launch_bounds__(256) void edge_kernel(
    const unsigned short* __restrict__ xlh, const float* __restrict__ xr,
    const float* __restrict__ h_in, const int* __restrict__ rowptr,
    const int* __restrict__ csr_src, const float* __restrict__ att,
    const float* __restrict__ bias, float* __restrict__ h_out, int N) {
  int wv = (blockIdx.x * blockDim.x + threadIdx.x) >> 6;
  int lane = threadIdx.x & 63;
  int g = lane >> 4, l16 = lane & 15;
  int v = wv * 4 + g;
  if (v >= N) return;
  float4 xr4 = *reinterpret_cast<const float4*>(&xr[(size_t)v * D + l16 * 4]);
  float4 at4 = *reinterpret_cast<const float4*>(&att[l16 * 4]);
  int beg = rowptr[v], end = rowptr[v + 1];
  int deg = end - beg;                       // >= 1 (self-loop)
  int glane0 = g << 4;
  float m = -INFINITY, s = 0.f;
  float ax = 0.f, ay = 0.f, az = 0.f, aw = 0.f;
  for (int sc = 0; sc < deg; sc += 16) {
    int us = csr_src[min(beg + sc + l16, end - 1)];   // 16 srcs ahead (clamped)
    int nt = min(16, deg - sc);
    for (int cc = 0; cc < nt; cc += 4) {
      float4 xu[4];
      float p[4];
#pragma unroll
      for (int k = 0; k < 4; ++k) {
        int u = __shfl(us, glane0 + cc + k, 64);      // group-local broadcast
        uint2 q = *reinterpret_cast<const uint2*>(&xlh[(size_t)u * D + l16 * 4]);
        xu[k].x = __uint_as_float(q.x << 16);
        xu[k].y = __uint_as_float(q.x & 0xFFFF0000u);
        xu[k].z = __uint_as_float(q.y << 16);
        xu[k].w = __uint_as_float(q.y & 0xFFFF0000u);
        float tx = xu[k].x + xr4.x, ty = xu[k].y + xr4.y;
        float tz = xu[k].z + xr4.z, tw = xu[k].w + xr4.w;
        tx = fmaxf(tx, 0.2f * tx);                    // leaky_relu slope 0.2
        ty = fmaxf(ty, 0.2f * ty);
        tz = fmaxf(tz, 0.2f * tz);
        tw = fmaxf(tw, 0.2f * tw);
        float pp = tx * at4.x + ty * at4.y + tz * at4.z + tw * at4.w;
        pp += __shfl_xor(pp, 1, 64);                  // 16-lane group reduce
        pp += __shfl_xor(pp, 2, 64);
        pp += __shfl_xor(pp, 4, 64);
        pp += __shfl_xor(pp, 8, 64);
        p[k] = (cc + k < nt) ? pp : -INFINITY;
      }
      float pm = fmaxf(fmaxf(p[0], p[1]), fmaxf(p[2], p[3]));
      float mn = fmaxf(m, pm);
      float a  = __expf(m - mn);                      // first chunk: 0
      float w0 = __expf(p[0] - mn);                   // invalid -> 0
      float w1 = __expf(p[1] - mn);
      float w2 = __expf(p[2] - mn);
      float w3 = __expf(p[3] - mn);
      s = s * a + (w0 + w1) + (w2 + w3);
      ax = fmaf(w0, xu[0].x, fmaf(w1, xu[1].x, fmaf(w2, xu[2].x, fmaf(w3, xu[3].x, ax * a))));
      ay = fmaf(w0, xu[0].y, fmaf(w1, xu[1].y, fmaf(w2, xu[2].y, fmaf(w3, xu[3].y, ay * a))));
      az = fmaf(w0, xu[0].z, fmaf(w1, xu[1].z, fmaf(w2, xu[2].z, fmaf(w3, xu[3].z, az * a))));
      aw = fmaf(w0, xu[0].w, fmaf(w1, xu[1].w, fmaf(w2, xu[2].w, fmaf(w3, xu[3].w, aw * a))));
      m = mn;
    }
  }
  float inv = 1.f / s;
  float4 b4v = *reinterpret_cast<const float4*>(&bias[l16 * 4]);
  float4 hv  = *reinterpret_cast<const float4*>(&h_in[(size_t)v * D + l16 * 4]);
  float4 o;
  o.x = fmaxf(ax * inv + b4v.x, 0.f) + hv.x;
  o.y = fmaxf(ay * inv + b4v.y, 0.f) + hv.y;
  o.z = fmaxf(az * inv + b4v.z, 0.f) + hv.z;
  o.w = fmaxf(aw * inv + b4v.w, 0.f) + hv.w;
  *reinterpret_cast<float4*>(&h_out[(size_t)v * D + l16 * 4]) = o;
}

// ---------------- launch ----------------

extern "C" void kernel_launch(void* const* d_in, const int* in_sizes, int n_in,
                              void* d_out, int out_size, void* d_ws, size_t ws_size,
                              hipStream_t stream) {
  const float* x    = (const float*)d_in[0];
  const int*   ei   = (const int*)d_in[1];
  const float* Wl   = (const float*)d_in[2];
  const float* bl   = (const float*)d_in[3];
  const float* Wr   = (const float*)d_in[4];
  const float* br   = (const float*)d_in[5];
  const float* att  = (const float*)d_in[6];
  const float* bias = (const float*)d_in[7];

  int N = in_sizes[0] / D;
  int E = in_sizes[1] / 2;
  int L = in_sizes[2] / (D * D);
  int EP = E + N;
  int NC = (N + (1 << CB) - 1) >> CB;   // coarse buckets (<= 64)
  int M = NC * NBLK;

  float* xr = (float*)d_ws;
  float* hA = xr + (size_t)N * D;
  float* hB = hA + (size_t)N * D;
  unsigned short* xlh = (unsigned short*)(hB + (size_t)N * D);
  unsigned* rec = (unsigned*)(xlh + (size_t)N * D);
  int* csr_src  = (int*)(rec + EP);
  int* rowptr   = csr_src + EP;
  int* ghist    = rowptr + (N + 1);
  int* cbase    = ghist + M;

  // CSR build (graph is layer-invariant: build once per call; every ghist/cbase
  // slot is written each call, so no memset needed)
  hist_coarse_kernel<<<NBLK, 256, 0, stream>>>(ei, ghist, E, N, NC);
  scan_coarse_kernel<<<1, 1024, 0, stream>>>(ghist, cbase, M, NC, EP);
  scatter_coarse_kernel<<<NBLK, 256, 0, stream>>>(ei, ghist, rec, E, N, NC);
  buildcsr2_kernel<<<NC, 1024, 0, stream>>>(rec, cbase, rowptr, csr_src, N, EP);

  int nwaves = (N + 3) / 4;                 // 4 nodes per wave
  int nblocks = (nwaves * 64 + 255) / 256;
  const float* h_in = x;
  for (int l = 0; l < L; ++l) {
    float* h_out = (l == L - 1) ? (float*)d_out : ((l % 2 == 0) ? hA : hB);
    transform_kernel<<<(N + 15) / 16, 256, 0, stream>>>(
        h_in, Wl + (size_t)l * D * D, bl + (size_t)l * D,
        Wr + (size_t)l * D * D, br + (size_t)l * D, xlh, xr, N);
    edge_kernel<<<nblocks, 256, 0, stream>>>(
        xlh, xr, h_in, rowptr, csr_src, att + (size_t)l * D,
        bias + (size_t)l * D, h_out, N);
    h_in = h_out;
  }
}